// Round 6
// baseline (115.548 us; speedup 1.0000x reference)
//
#include <hip/hip_runtime.h>
#include <math.h>

#define T     600
#define C     14
#define NOUT  500
#define W     128        // time window (64 lanes x 2 steps)
#define DSTR  132        // slow-path LDS stride; rows 0..13 = D, row 14 = zeros
#define CAP   64         // max (t,mask) events per row

typedef float f32x2 __attribute__((ext_vector_type(2)));

__device__ __forceinline__ float bperm(int addr, float v) {
    return __int_as_float(__builtin_amdgcn_ds_bpermute(addr, __float_as_int(v)));
}
__device__ __forceinline__ f32x2 fma2(f32x2 a, f32x2 b, f32x2 c) {
#if __has_builtin(__builtin_elementwise_fma)
    return __builtin_elementwise_fma(a, b, c);
#else
    f32x2 r; r.x = fmaf(a.x, b.x, c.x); r.y = fmaf(a.y, b.y, c.y); return r;
#endif
}

__global__ __launch_bounds__(64)
void snn_v6(const float* __restrict__ x, const float* __restrict__ W1,
            const float* __restrict__ W2, float* __restrict__ out) {
    __shared__ float    ds[15 * DSTR];   // slow path only
    __shared__ unsigned evs[CAP];        // (t<<14) | 14-bit channel mask

    const int  lane = threadIdx.x;
    const long row  = blockIdx.x;
    const float* xr = &x[row * (long)(C * T)];

    for (int i = lane; i < DSTR; i += 64) ds[14 * DSTR + i] = 0.f;  // zero pad row

    // ---- scan constants (once) ----
    const int   a1 = ((lane - 1) & 63) << 2;
    const int   a2 = ((lane - 2) & 63) << 2;
    const int   a4 = ((lane - 4) & 63) << 2;
    const int   a8 = ((lane - 8) & 63) << 2;
    const float m1 = (lane >= 1) ? 0.25f            : 0.f;
    const float m2 = (lane >= 2) ? 0.0625f          : 0.f;
    const float m4 = (lane >= 4) ? 0.00390625f      : 0.f;   // 0.25^4
    const float m8 = (lane >= 8) ? 1.52587890625e-5f: 0.f;   // 0.25^8
    const float kl = ldexpf(1.f, -2 * lane - 2);             // 0.25^(lane+1)

    float v1s[C];                        // wave-uniform per-channel LIF-1 state
    #pragma unroll
    for (int c = 0; c < C; ++c) v1s[c] = 0.f;
    int ecnt = 0;                        // wave-uniform event count

    // ---- prefetch window 0 ----
    f32x2 xv[C];
    #pragma unroll
    for (int j = 0; j < C; ++j)
        xv[j] = *(const f32x2*)&xr[j * T + 2 * lane];

    for (int t0 = 0; t0 < T; t0 += W) {
        const int wlen = (T - t0 < W) ? (T - t0) : W;    // 128,128,128,128,88

        // ===== GEMM (packed fp32): acc[c] = 0.5 * W1[c,:] . x[:, t-pair] =====
        f32x2 acc[C];
        #pragma unroll
        for (int c = 0; c < C; ++c) {
            f32x2 a = {0.f, 0.f};
            #pragma unroll
            for (int j = 0; j < C; ++j) {
                const float wv = 0.5f * W1[c * C + j];   // exact pow2 fold
                const f32x2 wvv = {wv, wv};
                a = fma2(xv[j], wvv, a);
            }
            acc[c] = a;
        }
        // ===== prefetch next window (stays in flight through scan) =====
        if (t0 + W < T) {
            const int tn = t0 + W + 2 * lane;
            #pragma unroll
            for (int j = 0; j < C; ++j) {
                const f32x2 z = {0.f, 0.f};
                xv[j] = (tn + 1 < T) ? *(const f32x2*)&xr[j * T + tn] : z;
            }
        }

        // ===== fast path: 4-step Kogge-Stone affine scan per channel =====
        bool  anyf = false;
        float wv_[C];
        #pragma unroll
        for (int c = 0; c < C; ++c) {
            const float de = acc[c].x, dd = acc[c].y;
            float S = fmaf(de, 0.5f, dd);                // segment value B
            S = fmaf(bperm(a1, S), m1, S);
            S = fmaf(bperm(a2, S), m2, S);
            S = fmaf(bperm(a4, S), m4, S);
            S = fmaf(bperm(a8, S), m8, S);
            const float Wv = fmaf(v1s[c], kl, S);        // v[2*lane+1]
            float tp = bperm(a1, Wv);                    // v at previous odd t
            tp = (lane == 0) ? v1s[c] : tp;
            const float ve = fmaf(tp, 0.5f, de);         // v[2*lane]
            anyf = anyf || (fmaxf(ve, Wv) >= 6.999f);    // margin: exact path decides
            wv_[c] = Wv;
        }
        const int lastl = (wlen >> 1) - 1;

        if (__builtin_expect(__ballot(anyf) != 0ull, 0)) {
            // ===== exact slow path (rare, wave-uniform): v5 serial chain =====
            #pragma unroll
            for (int c = 0; c < C; ++c)
                *(f32x2*)&ds[c * DSTR + 2 * lane] = acc[c];
            __builtin_amdgcn_wave_barrier();
            float vv = 0.f;
            #pragma unroll
            for (int c = 0; c < C; ++c) vv = (lane == c) ? v1s[c] : vv;
            const int ce = (lane < C) ? lane : 14;
            const float* dp = &ds[ce * DSTR];
            for (int q = 0; q < wlen; q += 4) {
                const float4 hd = *(const float4*)&dp[q];
                const float A  = fmaf(vv, 0.5f, hd.x);
                const float Bq = fmaf(A,  0.5f, hd.y);
                const float Cq = fmaf(Bq, 0.5f, hd.z);
                const float Dq = fmaf(Cq, 0.5f, hd.w);
                const float Mq = fmaxf(fmaxf(A, Bq), fmaxf(Cq, Dq));
                if (__ballot(Mq >= 7.0f)) {
                    float vp = vv;                        // exact replay
                    #pragma unroll
                    for (int u = 0; u < 4; ++u) {
                        const float h = (u==0)?hd.x:(u==1)?hd.y:(u==2)?hd.z:hd.w;
                        vp = fmaf(vp, 0.5f, h);
                        const unsigned long long bal = __ballot(vp >= 7.0f);
                        if (bal) {
                            if (vp >= 7.0f) vp = 0.5f;    // reset + exact cache fold
                            if (ecnt < CAP && lane == 0)
                                evs[ecnt] = ((unsigned)(t0 + q + u) << 14)
                                          | ((unsigned)bal & 0x3FFFu);
                            ++ecnt;
                        }
                    }
                    vv = vp;
                } else {
                    vv = Dq;                              // bitwise exact skip
                }
            }
            __builtin_amdgcn_wave_barrier();
            #pragma unroll
            for (int c = 0; c < C; ++c) v1s[c] = __shfl(vv, c, 64);
        } else {
            #pragma unroll
            for (int c = 0; c < C; ++c) v1s[c] = __shfl(wv_[c], lastl, 64);
        }
    }
    __builtin_amdgcn_wave_barrier();

    // ===== event-driven LIF-2 + exp: 64 lanes x 8 outputs =====
    const int n = (ecnt < CAP) ? ecnt : CAP;
    float v2[8];
    #pragma unroll
    for (int k = 0; k < 8; ++k) v2[k] = 0.f;
    int tprev = -1;

    for (int e = 0; e < n; ++e) {
        const unsigned ev = evs[e];
        const int t = (int)(ev >> 14);
        unsigned mm = ev & 0x3FFFu;
        float i2[8];
        #pragma unroll
        for (int k = 0; k < 8; ++k) i2[k] = 0.f;
        while (mm) {                         // ascending channels = ref dot order
            const int c = (int)__builtin_ctz(mm);
            mm &= mm - 1;
            #pragma unroll
            for (int k = 0; k < 8; ++k) {
                const int o = lane + (k << 6);
                if (o < NOUT) i2[k] += W2[o * C + c];
            }
        }
        const int gap = t - tprev - 1;
        if (gap > 0) {                       // exact pure-decay run
            #pragma unroll
            for (int k = 0; k < 8; ++k) v2[k] = ldexpf(v2[k], -gap);
        }
        #pragma unroll
        for (int k = 0; k < 8; ++k) {
            const float v = v2[k] + (i2[k] - v2[k]) * 0.5f;   // ref-order charge
            v2[k] = (v >= 7.0f) ? 0.f : v;                    // hard reset
        }
        tprev = t;
    }
    {
        const int gap = (T - 1) - tprev;
        if (gap > 0) {
            #pragma unroll
            for (int k = 0; k < 8; ++k) v2[k] = ldexpf(v2[k], -gap);
        }
    }
    #pragma unroll
    for (int k = 0; k < 8; ++k) {
        const int o = lane + (k << 6);
        if (o < NOUT) out[row * NOUT + o] = expf(v2[k]);
    }
}

extern "C" void kernel_launch(void* const* d_in, const int* in_sizes, int n_in,
                              void* d_out, int out_size, void* d_ws, size_t ws_size,
                              hipStream_t stream) {
    const float* x  = (const float*)d_in[0];
    const float* W1 = (const float*)d_in[1];
    const float* W2 = (const float*)d_in[2];
    float* o = (float*)d_out;
    const int B = in_sizes[0] / (C * T);     // 4096
    snn_v6<<<B, 64, 0, stream>>>(x, W1, W2, o);
}

// Round 7
// 57.256 us; speedup vs baseline: 2.0181x; 2.0181x over previous
//
#include <hip/hip_runtime.h>
#include <math.h>

#define T     600
#define C     14
#define NOUT  500
#define W     128        // steps per window (64 lanes x 2)
#define DSTR  132        // padded D row stride (floats): banks spread 4/row
#define CAP   64         // max (t,mask) events per row

typedef float f32x2 __attribute__((ext_vector_type(2)));

__global__ __launch_bounds__(64, 4)
void snn_v7(const float* __restrict__ x, const float* __restrict__ W1,
            const float* __restrict__ W2, float* __restrict__ out) {
    __shared__ float    D[C * DSTR];     // 7392 B, half-current window
    __shared__ unsigned evs[CAP];        // (t<<14) | 14-bit channel mask

    const int  lane = threadIdx.x;
    const long row  = blockIdx.x;
    const float* xr = &x[row * (long)(C * T)];
    const int  ce   = (lane < C) ? lane : (C - 1);   // chain source (dupes mirror c=13)

    // ---- prefetch window 0 into registers ----
    f32x2 xv[C];
    #pragma unroll
    for (int j = 0; j < C; ++j)
        xv[j] = *(const f32x2*)&xr[j * T + 2 * lane];

    float v1 = 0.f;
    int   ecnt = 0;                      // wave-uniform event count

    for (int w = 0; w < 5; ++w) {
        const int t0 = w * W;

        // ---- fold: xh = 0.5*x (exact), frees xv for next prefetch ----
        f32x2 xh[C];
        #pragma unroll
        for (int j = 0; j < C; ++j) xh[j] = xv[j] * 0.5f;

        // ---- issue next-window x loads NOW (hide under GEMM + chain) ----
        if (w < 4) {
            const int tn = t0 + W + 2 * lane;
            #pragma unroll
            for (int j = 0; j < C; ++j) {
                const f32x2 z = {0.f, 0.f};
                xv[j] = (tn + 1 < T) ? *(const f32x2*)&xr[j * T + tn] : z;
            }
        }

        // ---- GEMM: D[c][t-pair] = sum_j W1[c][j] * xh[j]  (raw W1 sgprs) ----
        #pragma unroll
        for (int c = 0; c < C; ++c) {
            f32x2 a = {0.f, 0.f};
            #pragma unroll
            for (int j = 0; j < C; ++j) {
                const float wv = W1[c * C + j];
                a.x = fmaf(xh[j].x, wv, a.x);
                a.y = fmaf(xh[j].y, wv, a.y);
            }
            *(f32x2*)&D[c * DSTR + 2 * lane] = a;
        }

        // drain LDS writes (vmcnt prefetch stays in flight); fence scheduler
        asm volatile("s_waitcnt lgkmcnt(0)" ::: "memory");
        __builtin_amdgcn_sched_barrier(0);

        // ---- LIF-1 chain: spec-16 batches, LDS prefetch 1 batch ahead ----
        const float* dp = &D[ce * DSTR];
        const int nb = (w < 4) ? 8 : 6;              // 128 or 96 (88 + zero pad)
        float4 c0 = *(const float4*)&dp[0];
        float4 c1 = *(const float4*)&dp[4];
        float4 c2 = *(const float4*)&dp[8];
        float4 c3 = *(const float4*)&dp[12];
        for (int b = 0; b < nb; ++b) {
            float4 n0, n1, n2, n3;
            const bool more = (b + 1 < nb);
            if (more) {
                const float* np_ = dp + 16 * (b + 1);
                n0 = *(const float4*)&np_[0];
                n1 = *(const float4*)&np_[4];
                n2 = *(const float4*)&np_[8];
                n3 = *(const float4*)&np_[12];
            }
            float h[16];
            h[0]=c0.x; h[1]=c0.y; h[2]=c0.z; h[3]=c0.w;
            h[4]=c1.x; h[5]=c1.y; h[6]=c1.z; h[7]=c1.w;
            h[8]=c2.x; h[9]=c2.y; h[10]=c2.z; h[11]=c2.w;
            h[12]=c3.x; h[13]=c3.y; h[14]=c3.z; h[15]=c3.w;

            float vv = v1;
            float m0 = -1e30f, m1 = -1e30f, m2 = -1e30f, m3 = -1e30f;
            #pragma unroll
            for (int u = 0; u < 16; u += 4) {        // 4 parallel max chains
                vv = fmaf(vv, 0.5f, h[u]);     m0 = fmaxf(m0, vv);
                vv = fmaf(vv, 0.5f, h[u + 1]); m1 = fmaxf(m1, vv);
                vv = fmaf(vv, 0.5f, h[u + 2]); m2 = fmaxf(m2, vv);
                vv = fmaf(vv, 0.5f, h[u + 3]); m3 = fmaxf(m3, vv);
            }
            const float mx = fmaxf(fmaxf(m0, m1), fmaxf(m2, m3));

            if (__builtin_expect(__ballot(mx >= 7.0f) != 0ull, 0)) {
                float vp = v1;                       // exact replay with resets
                #pragma unroll
                for (int u = 0; u < 16; ++u) {
                    vp = fmaf(vp, 0.5f, h[u]);
                    const unsigned long long bal = __ballot(vp >= 7.0f);
                    if (bal) {
                        if (vp >= 7.0f) vp = 0.5f;   // reset + exact cache fold
                        if (lane == 0 && ecnt < CAP)
                            evs[ecnt] = ((unsigned)(t0 + 16 * b + u) << 14)
                                      | ((unsigned)bal & 0x3FFFu);
                        ++ecnt;                      // uniform
                    }
                }
                v1 = vp;
            } else {
                v1 = vv;                             // bitwise exact (no spike)
            }
            if (more) { c0 = n0; c1 = n1; c2 = n2; c3 = n3; }
        }
    }

    // ---- make evs visible (same wave, in-order; drain + fence) ----
    asm volatile("s_waitcnt lgkmcnt(0)" ::: "memory");
    __builtin_amdgcn_sched_barrier(0);

    // ===== event-driven LIF-2 + exp: 64 lanes x 8 outputs =====
    const int n = (ecnt < CAP) ? ecnt : CAP;
    float v2[8];
    #pragma unroll
    for (int k = 0; k < 8; ++k) v2[k] = 0.f;
    int tprev = -1;

    for (int e = 0; e < n; ++e) {
        const unsigned ev = evs[e];
        const int t = (int)(ev >> 14);
        unsigned mm = ev & 0x3FFFu;
        float i2[8];
        #pragma unroll
        for (int k = 0; k < 8; ++k) i2[k] = 0.f;
        while (mm) {                         // ascending channels = ref dot order
            const int c = (int)__builtin_ctz(mm);
            mm &= mm - 1;
            #pragma unroll
            for (int k = 0; k < 8; ++k) {
                const int o = lane + (k << 6);
                if (o < NOUT) i2[k] += W2[o * C + c];
            }
        }
        const int gap = t - tprev - 1;
        if (gap > 0) {                       // exact pure-decay run
            #pragma unroll
            for (int k = 0; k < 8; ++k) v2[k] = ldexpf(v2[k], -gap);
        }
        #pragma unroll
        for (int k = 0; k < 8; ++k) {
            const float v = v2[k] + (i2[k] - v2[k]) * 0.5f;   // ref-order charge
            v2[k] = (v >= 7.0f) ? 0.f : v;                    // hard reset
        }
        tprev = t;
    }
    {
        const int gap = (T - 1) - tprev;
        if (gap > 0) {
            #pragma unroll
            for (int k = 0; k < 8; ++k) v2[k] = ldexpf(v2[k], -gap);
        }
    }
    #pragma unroll
    for (int k = 0; k < 8; ++k) {
        const int o = lane + (k << 6);
        if (o < NOUT) out[row * NOUT + o] = expf(v2[k]);
    }
}

extern "C" void kernel_launch(void* const* d_in, const int* in_sizes, int n_in,
                              void* d_out, int out_size, void* d_ws, size_t ws_size,
                              hipStream_t stream) {
    const float* x  = (const float*)d_in[0];
    const float* W1 = (const float*)d_in[1];
    const float* W2 = (const float*)d_in[2];
    float* o = (float*)d_out;
    const int B = in_sizes[0] / (C * T);     // 4096
    snn_v7<<<B, 64, 0, stream>>>(x, W1, W2, o);
}

// Round 8
// 47.810 us; speedup vs baseline: 2.4168x; 1.1976x over previous
//
#include <hip/hip_runtime.h>
#include <math.h>

#define T     600
#define C     14
#define NOUT  500
#define W     128        // steps per window
#define NWIN  5
#define DSTR  132        // D-buffer row stride (floats) — bank spread
#define CAP   64         // max (t,mask) events per row

typedef float f32x2 __attribute__((ext_vector_type(2)));

__device__ __forceinline__ void stage16(const float* gp, float* lp) {
    __builtin_amdgcn_global_load_lds(
        (const __attribute__((address_space(1))) void*)(gp),
        (__attribute__((address_space(3))) void*)(lp), 16, 0, 0);
}

__global__ __launch_bounds__(64)
void snn_v8(const float* __restrict__ x, const float* __restrict__ W1,
            const float* __restrict__ W2, float* __restrict__ out) {
    __shared__ float    xs[448 * 4];     // 7168 B: 448 swizzled 16B granules
    __shared__ float    db[C * DSTR];    // 7392 B: D window (padded rows)
    __shared__ unsigned evs[CAP];        // (t<<14) | 14-bit channel mask

    const int  lane = threadIdx.x;
    const long row  = blockIdx.x;
    const float* xr = &x[row * (long)(C * T)];
    const int  ce   = (lane < C) ? lane : (C - 1);   // chain source channel

    // ---- staging source ptrs: slot s=64k+lane; j=s>>5; g=(s-j)&31 ----
    // LDS granule s holds x[j][t0+4g .. t0+4g+3]; lds byte = 16*s (linear DMA)
    const float* gsrc[7];
    #pragma unroll
    for (int k = 0; k < 7; ++k) {
        const int s = 64 * k + lane;
        const int j = s >> 5;
        const int g = (s - j) & 31;
        gsrc[k] = xr + j * T + 4 * g;
    }
    // ---- GEMM LDS read byte-offsets (one per channel, static) ----
    int xadr[C];
    #pragma unroll
    for (int j = 0; j < C; ++j)
        xadr[j] = 16 * (32 * j + (((lane >> 1) + j) & 31)) + 8 * (lane & 1);

    // ---- issue window-0 staging ----
    #pragma unroll
    for (int k = 0; k < 7; ++k)
        stage16(gsrc[k], &xs[k * 256]);

    float v1 = 0.f;
    int   ecnt = 0;                      // wave-uniform event count

    for (int w = 0; w < NWIN; ++w) {
        const int t0 = w * W;
        asm volatile("s_waitcnt vmcnt(0)" ::: "memory");   // x(w) landed in LDS
        __builtin_amdgcn_sched_barrier(0);

        // ===== GEMM: D[c][t-pair] = sum_j W1[c][j] * (0.5*x[j]) =====
        f32x2 xv[C];
        #pragma unroll
        for (int j = 0; j < C; ++j)
            xv[j] = *(const f32x2*)((const char*)xs + xadr[j]);
        // tail window: steps >= 88 get D=0 (exact zero-pad; stale LDS discarded)
        const float msk = (w == NWIN - 1 && 2 * lane >= T - 512) ? 0.f : 0.5f;
        #pragma unroll
        for (int j = 0; j < C; ++j) { xv[j].x *= msk; xv[j].y *= msk; }
        #pragma unroll
        for (int c = 0; c < C; ++c) {
            f32x2 a = {0.f, 0.f};
            #pragma unroll
            for (int j = 0; j < C; ++j) {
                const float wv = W1[c * C + j];
                a.x = fmaf(xv[j].x, wv, a.x);
                a.y = fmaf(xv[j].y, wv, a.y);
            }
            *(f32x2*)&db[c * DSTR + 2 * lane] = a;
        }
        asm volatile("s_waitcnt lgkmcnt(0)" ::: "memory");  // xs reads + db writes done
        __builtin_amdgcn_sched_barrier(0);

        // ===== issue next-window staging (in flight through chain) =====
        if (w + 1 < NWIN) {
            if (w + 1 < NWIN - 1) {
                #pragma unroll
                for (int k = 0; k < 7; ++k) {
                    gsrc[k] += W;
                    stage16(gsrc[k], &xs[k * 256]);
                }
            } else {                       // tail: only granules with t < T
                #pragma unroll
                for (int k = 0; k < 7; ++k) {
                    gsrc[k] += W;
                    const int s = 64 * k + lane;
                    const int g = (s - (s >> 5)) & 31;
                    if (4 * g < T - 512)
                        stage16(gsrc[k], &xs[k * 256]);
                }
            }
        }

        // ===== LIF-1 chain: spec-16 batches, LDS prefetch 1 batch ahead =====
        const float* dp = &db[ce * DSTR];
        const int nb = (w < NWIN - 1) ? 8 : 6;   // 128 or 96 (88 + zero pad)
        float4 c0 = *(const float4*)&dp[0];
        float4 c1 = *(const float4*)&dp[4];
        float4 c2 = *(const float4*)&dp[8];
        float4 c3 = *(const float4*)&dp[12];
        for (int b = 0; b < nb; ++b) {
            float4 n0, n1, n2, n3;
            const bool more = (b + 1 < nb);
            if (more) {
                const float* np_ = dp + 16 * (b + 1);
                n0 = *(const float4*)&np_[0];
                n1 = *(const float4*)&np_[4];
                n2 = *(const float4*)&np_[8];
                n3 = *(const float4*)&np_[12];
            }
            float h[16];
            h[0]=c0.x; h[1]=c0.y; h[2]=c0.z; h[3]=c0.w;
            h[4]=c1.x; h[5]=c1.y; h[6]=c1.z; h[7]=c1.w;
            h[8]=c2.x; h[9]=c2.y; h[10]=c2.z; h[11]=c2.w;
            h[12]=c3.x; h[13]=c3.y; h[14]=c3.z; h[15]=c3.w;

            float vv = v1;
            float m0 = -1e30f, m1 = -1e30f, m2 = -1e30f, m3 = -1e30f;
            #pragma unroll
            for (int u = 0; u < 16; u += 4) {    // 4 parallel max chains
                vv = fmaf(vv, 0.5f, h[u]);     m0 = fmaxf(m0, vv);
                vv = fmaf(vv, 0.5f, h[u + 1]); m1 = fmaxf(m1, vv);
                vv = fmaf(vv, 0.5f, h[u + 2]); m2 = fmaxf(m2, vv);
                vv = fmaf(vv, 0.5f, h[u + 3]); m3 = fmaxf(m3, vv);
            }
            const float mx = fmaxf(fmaxf(m0, m1), fmaxf(m2, m3));

            if (__builtin_expect(__ballot(mx >= 7.0f) != 0ull, 0)) {
                float vp = v1;                   // exact replay with resets
                #pragma unroll
                for (int u = 0; u < 16; ++u) {
                    vp = fmaf(vp, 0.5f, h[u]);
                    const unsigned long long bal = __ballot(vp >= 7.0f);
                    if (bal) {
                        if (vp >= 7.0f) vp = 0.5f;   // reset + exact cache fold
                        if (lane == 0 && ecnt < CAP)
                            evs[ecnt] = ((unsigned)(t0 + 16 * b + u) << 14)
                                      | ((unsigned)bal & 0x3FFFu);
                        ++ecnt;                      // wave-uniform
                    }
                }
                v1 = vp;
            } else {
                v1 = vv;                             // no spike: bitwise exact
            }
            if (more) { c0 = n0; c1 = n1; c2 = n2; c3 = n3; }
        }
    }

    asm volatile("s_waitcnt lgkmcnt(0)" ::: "memory");
    __builtin_amdgcn_sched_barrier(0);

    // ===== event-driven LIF-2 + exp: 64 lanes x 8 outputs =====
    const int n = (ecnt < CAP) ? ecnt : CAP;
    float v2[8];
    #pragma unroll
    for (int k = 0; k < 8; ++k) v2[k] = 0.f;
    int tprev = -1;

    for (int e = 0; e < n; ++e) {
        const unsigned ev = evs[e];
        const int t = (int)(ev >> 14);
        unsigned mm = ev & 0x3FFFu;
        float i2[8];
        #pragma unroll
        for (int k = 0; k < 8; ++k) i2[k] = 0.f;
        while (mm) {                         // ascending channels = ref dot order
            const int c = (int)__builtin_ctz(mm);
            mm &= mm - 1;
            #pragma unroll
            for (int k = 0; k < 8; ++k) {
                const int o = lane + (k << 6);
                if (o < NOUT) i2[k] += W2[o * C + c];
            }
        }
        const int gap = t - tprev - 1;
        if (gap > 0) {                       // exact pure-decay run
            #pragma unroll
            for (int k = 0; k < 8; ++k) v2[k] = ldexpf(v2[k], -gap);
        }
        #pragma unroll
        for (int k = 0; k < 8; ++k) {
            const float v = v2[k] + (i2[k] - v2[k]) * 0.5f;   // ref-order charge
            v2[k] = (v >= 7.0f) ? 0.f : v;                    // hard reset
        }
        tprev = t;
    }
    {
        const int gap = (T - 1) - tprev;
        if (gap > 0) {
            #pragma unroll
            for (int k = 0; k < 8; ++k) v2[k] = ldexpf(v2[k], -gap);
        }
    }
    #pragma unroll
    for (int k = 0; k < 8; ++k) {
        const int o = lane + (k << 6);
        if (o < NOUT) out[row * NOUT + o] = expf(v2[k]);
    }
}

extern "C" void kernel_launch(void* const* d_in, const int* in_sizes, int n_in,
                              void* d_out, int out_size, void* d_ws, size_t ws_size,
                              hipStream_t stream) {
    const float* x  = (const float*)d_in[0];
    const float* W1 = (const float*)d_in[1];
    const float* W2 = (const float*)d_in[2];
    float* o = (float*)d_out;
    const int B = in_sizes[0] / (C * T);     // 4096
    snn_v8<<<B, 64, 0, stream>>>(x, W1, W2, o);
}